// Round 6
// baseline (815.017 us; speedup 1.0000x reference)
//
#include <hip/hip_runtime.h>
#include <cstdint>

#define VOCAB 100000
#define EMB 300
#define NE 301         // 300 emb dims + 1 bias row (evoke_b)
#define KP 128         // padded h (bf16 elements per p-row)
#define EKSTRIDE 28672 // bytes per e slab = 7 tiles * 4 ks * 1024 B
#define NP 128         // G row stride (floats)
#define BM 64
#define BTOT 16384
#define EMBL_BYTES 77056               // [301][128] bf16
#define EKB_OFF EMBL_BYTES             // double-buffered slab after embl
#define LDS_TOTAL (EMBL_BYTES + 2 * EKSTRIDE)   // 134,400 B

typedef __attribute__((ext_vector_type(8))) short short8;
typedef __attribute__((ext_vector_type(4))) float f32x4;

__device__ __forceinline__ unsigned short f2bf(float f) {
    uint32_t u = __float_as_uint(f);
    uint32_t r = (u + 0x7fffu + ((u >> 16) & 1u)) >> 16;   // RNE
    return (unsigned short)r;
}

// ---------------------------------------------------------------------------
// Prep 1: pack evoke_k (+ evoke_b as e=300) into bf16 FRAG-ORDERED layout:
// byte offset = e*EKSTRIDE + ((t*4 + ks)*64 + lane)*16, where the 16 B hold
// ek[p = t*16 + (lane&15)][h = ks*32 + (lane>>4)*8 .. +7]  (zero-padded).
// k_main stages a slab to LDS with global_load_lds; frags read lane-linear.
// ---------------------------------------------------------------------------
__global__ __launch_bounds__(256) void k_ekprep(const float* __restrict__ evoke_k,
                                                const float* __restrict__ evoke_b,
                                                unsigned short* __restrict__ ekp) {
    int e = blockIdx.x;            // 0..300
    const float* src = (e < EMB) ? (evoke_k + (size_t)e * 10000) : evoke_b;
    uint32_t* dst = (uint32_t*)(ekp + (size_t)e * (EKSTRIDE / 2));
#pragma unroll
    for (int it = 0; it < 7; ++it) {
        int c    = it * 256 + threadIdx.x;   // chunk-lane id 0..1791
        int lane = c & 63;
        int ks   = (c >> 6) & 3;
        int t    = c >> 8;                   // 0..6
        int p    = t * 16 + (lane & 15);
        int h0   = ks * 32 + (lane >> 4) * 8;
        uint32_t ov[4] = {0u, 0u, 0u, 0u};
        if (p < 100) {
#pragma unroll
            for (int j = 0; j < 8; ++j) {
                int h = h0 + j;
                float f = (h < 100) ? src[p * 100 + h] : 0.f;
                ov[j >> 1] |= (uint32_t)f2bf(f) << ((j & 1) * 16);
            }
        }
        uint32_t* o = dst + (size_t)c * 4;
        o[0] = ov[0]; o[1] = ov[1]; o[2] = ov[2]; o[3] = ov[3];
    }
}

// ---------------------------------------------------------------------------
// Prep 2: time MLP -> tv, stored bf16 [B][128] (h padded with zeros)
// ---------------------------------------------------------------------------
__global__ __launch_bounds__(256) void k_tv(const float* __restrict__ times,
                                            const float* __restrict__ h1_k,
                                            const float* __restrict__ h1_b,
                                            const float* __restrict__ h2_k,
                                            const float* __restrict__ h2_b,
                                            unsigned short* __restrict__ tvp) {
    __shared__ float h1s[16][100];
    int b0 = blockIdx.x * 16;
    for (int idx = threadIdx.x; idx < 1600; idx += 256) {
        int bb = idx / 100, i = idx - bb * 100;
        h1s[bb][i] = tanhf(times[b0 + bb] * h1_k[i] + h1_b[i]);
    }
    __syncthreads();
    for (int idx = threadIdx.x; idx < 1600; idx += 256) {
        int bb = idx / 100, j = idx - bb * 100;
        float acc = h2_b[j];
        for (int i = 0; i < 100; ++i) acc += h1s[bb][i] * h2_k[i * 100 + j];
        tvp[(size_t)(b0 + bb) * KP + j] = f2bf(tanhf(acc));
    }
    for (int idx = threadIdx.x; idx < 16 * 28; idx += 256) {
        int bb = idx / 28, j = 100 + (idx - bb * 28);
        tvp[(size_t)(b0 + bb) * KP + j] = 0;
    }
}

// ---------------------------------------------------------------------------
// Prep 3: G = last_k last_k^T (padded 128x128), v = last_k last_b, c0 = |last_b|^2.
// Also zeroes d_out (runs before main kernel's atomics).
// ---------------------------------------------------------------------------
__global__ __launch_bounds__(128) void k_gprep(const float* __restrict__ last_k,
                                               const float* __restrict__ last_b,
                                               float* __restrict__ G,
                                               float* __restrict__ vvec,
                                               float* __restrict__ c0,
                                               float* __restrict__ out) {
    int p = blockIdx.x;   // 0..127
    int q = threadIdx.x;  // 0..127
    __shared__ float row[EMB];
    for (int d = q; d < EMB; d += 128) row[d] = (p < 100) ? last_k[p * EMB + d] : 0.f;
    __syncthreads();
    float acc = 0.f;
    if (p < 100 && q < 100) {
        for (int d = 0; d < EMB; ++d) acc += row[d] * last_k[q * EMB + d];
    }
    G[p * NP + q] = acc;
    if (q == 0) {
        float a = 0.f;
        if (p < 100) {
            for (int d = 0; d < EMB; ++d) a += row[d] * last_b[d];
        }
        vvec[p] = a;
        if (p == 0) {
            float s = 0.f;
            for (int d = 0; d < EMB; ++d) s += last_b[d] * last_b[d];
            *c0 = s;
            *out = 0.f;
        }
    }
}

// ---------------------------------------------------------------------------
// Main: 64 batch rows x 112 p per block, 256 threads = 4 waves, 256 blocks =
// 1 block/CU (32 blocks/XCD -- halves the per-XCD L2 request volume vs BM=32;
// r4 showed the wall is L2 line-service rate on the shared ekp stream, ~4
// lines/cyc/XCD).  The e-slab is DMA-staged into a double-buffered LDS region
// with global_load_lds (no VGPR destination -> nothing for the scheduler to
// collapse, the r3/r4/r5 failure mode).  One __syncthreads per e; stage(e+1)
// is in flight across the whole compute(e) phase.
// ---------------------------------------------------------------------------
__global__ __launch_bounds__(256, 1) void k_main(
    const int* __restrict__ targets, const int* __restrict__ contexts,
    const float* __restrict__ labels,
    const float* __restrict__ targetemb, const float* __restrict__ contextemb,
    const unsigned short* __restrict__ ekp, const unsigned short* __restrict__ tvp,
    const float* __restrict__ G, const float* __restrict__ vvec,
    const float* __restrict__ c0p, float* __restrict__ out) {
    extern __shared__ char smem[];
    // [0, 77056)          : embl bf16 [301 e][2 br][64 b]
    // [77056, 134400)     : ekb bf16, 2 x 28672-B slab double-buffer
    // epilogue aliases [0, 57344): mv_t [64][112], mv_c [64][112]
    __shared__ float bsum[4];

    const int tid  = threadIdx.x;
    const int lane = tid & 63;
    const int w    = tid >> 6;       // wave 0..3
    const int l15  = lane & 15;
    const int l4   = lane >> 4;      // 0..3
    const int m0   = blockIdx.x * BM;

    unsigned short* embl = (unsigned short*)smem;
    unsigned short* ekb  = (unsigned short*)(smem + EKB_OFF);

    // ---- stationary tv A-frags (bf16): m = l15, k-chunk = ks*32 + l4*8 ----
    short8 afrag[4][4];
#pragma unroll
    for (int mt = 0; mt < 4; ++mt) {
        int bg = m0 + mt * 16 + l15;
#pragma unroll
        for (int ks = 0; ks < 4; ++ks) {
            afrag[mt][ks] = *(const short8*)(tvp + (size_t)bg * KP + ks * 32 + l4 * 8);
        }
    }

    // ---- per-wave B-frag activity + LDS short-offsets within a slab ----
    bool act[2];
    int  soff[2][4];                 // offsets in shorts into a 28672-B slab
#pragma unroll
    for (int nt = 0; nt < 2; ++nt) {
        int t = w * 2 + nt;          // n-tile 0..7; tile 7 doesn't exist (p<112)
        act[nt] = (t < 7);
#pragma unroll
        for (int ks = 0; ks < 4; ++ks) {
            soff[nt][ks] = (t < 7) ? ((t * 4 + ks) * 512 + lane * 8) : 0;
        }
    }

    // ---- async DMA stage of slab ei into LDS buffer bufi ----
    auto stage = [&](int bufi, int ei) {
        const char* slab = (const char*)ekp + (size_t)ei * EKSTRIDE;
        char* dstb = (char*)ekb + bufi * EKSTRIDE;
#pragma unroll
        for (int r = 0; r < 7; ++r) {
            int chunk = (r * 4 + w) * 1024;          // wave-uniform
            __builtin_amdgcn_global_load_lds(
                (const __attribute__((address_space(1))) uint32_t*)(slab + chunk + lane * 16),
                (__attribute__((address_space(3))) uint32_t*)(dstb + chunk),
                16, 0, 0);
        }
    };

    // ---- prologue: stage slab 0, stage all emb scalars, one barrier ----
    stage(0, 0);
    {
        int off    = tid & 127;                   // branch*64 + b
        int b      = off & 63;
        int branch = off >> 6;
        int seg    = tid >> 7;                    // 0..1
        int s0 = seg * 152;
        int s1 = seg ? 300 : 152;                 // 152 / 148 rows, both %4==0
        const int* idxp   = branch ? contexts : targets;
        const float* base = branch ? contextemb : targetemb;
        const float* row  = base + (size_t)idxp[m0 + b] * EMB;
        for (int e = s0; e + 3 < s1; e += 4) {
            float4 v = *(const float4*)(row + e);
            embl[(e + 0) * 128 + off] = f2bf(v.x);
            embl[(e + 1) * 128 + off] = f2bf(v.y);
            embl[(e + 2) * 128 + off] = f2bf(v.z);
            embl[(e + 3) * 128 + off] = f2bf(v.w);
        }
        if (seg == 1) embl[300 * 128 + off] = 0x3F80;   // bias row e=300 -> 1.0
    }

    f32x4 acc_t[4][2], acc_c[4][2];
    const f32x4 zf = {0.f, 0.f, 0.f, 0.f};
#pragma unroll
    for (int mt = 0; mt < 4; ++mt) {
#pragma unroll
        for (int nt = 0; nt < 2; ++nt) { acc_t[mt][nt] = zf; acc_c[mt][nt] = zf; }
    }

    auto compute = [&](int el, int bufi) {
        const unsigned short* ekbuf = ekb + bufi * (EKSTRIDE / 2);
        // emb scalars for this e (broadcast LDS reads, bf16 -> fp32 unpack)
        float et[4][4], ec[4][4];
#pragma unroll
        for (int mt = 0; mt < 4; ++mt) {
            int row0 = mt * 16 + l4 * 4;
            uint2 dt = *(const uint2*)(embl + el * 128 + row0);
            uint2 dc = *(const uint2*)(embl + el * 128 + 64 + row0);
            et[mt][0] = __uint_as_float(dt.x << 16);
            et[mt][1] = __uint_as_float(dt.x & 0xffff0000u);
            et[mt][2] = __uint_as_float(dt.y << 16);
            et[mt][3] = __uint_as_float(dt.y & 0xffff0000u);
            ec[mt][0] = __uint_as_float(dc.x << 16);
            ec[mt][1] = __uint_as_float(dc.x & 0xffff0000u);
            ec[mt][2] = __uint_as_float(dc.y << 16);
            ec[mt][3] = __uint_as_float(dc.y & 0xffff0000u);
        }
#pragma unroll
        for (int nt = 0; nt < 2; ++nt) {
            if (act[nt]) {
                short8 bfrag[4];
#pragma unroll
                for (int ks = 0; ks < 4; ++ks) {
                    bfrag[ks] = *(const short8*)(ekbuf + soff[nt][ks]);
                }
                f32x4 S[4];
#pragma unroll
                for (int mt = 0; mt < 4; ++mt) S[mt] = zf;
#pragma unroll
                for (int ks = 0; ks < 4; ++ks) {
#pragma unroll
                    for (int mt = 0; mt < 4; ++mt) {
                        S[mt] = __builtin_amdgcn_mfma_f32_16x16x32_bf16(
                            afrag[mt][ks], bfrag[ks], S[mt], 0, 0, 0);
                    }
                }
#pragma unroll
                for (int mt = 0; mt < 4; ++mt) {
#pragma unroll
                    for (int r = 0; r < 4; ++r) {
                        acc_t[mt][nt][r] += et[mt][r] * S[mt][r];
                        acc_c[mt][nt][r] += ec[mt][r] * S[mt][r];
                    }
                }
            }
        }
    };

    __syncthreads();   // slab 0 staged (compiler drains vmcnt) + embl ready

    // ---- 2-phase pipelined e-loop: stage(e+1) in flight under compute(e) ----
#pragma unroll 1
    for (int e = 0; e < 300; ++e) {
        stage((e + 1) & 1, e + 1);
        compute(e, e & 1);
        __syncthreads();             // drains the stage DMA + LDS reads
    }
    compute(300, 0);                 // e = 300 (bias row)

    // ---- epilogue ----
    __syncthreads();
    float* mvt = (float*)smem;              // [64][112]
    float* mvc = (float*)(smem + 28672);    // [64][112]
#pragma unroll
    for (int mt = 0; mt < 4; ++mt) {
#pragma unroll
        for (int nt = 0; nt < 2; ++nt) {
            if (act[nt]) {
                int col = (w * 2 + nt) * 16 + l15;   // 0..111
#pragma unroll
                for (int r = 0; r < 4; ++r) {
                    int row = mt * 16 + l4 * 4 + r;
                    mvt[row * 112 + col] = acc_t[mt][nt][r];
                    mvc[row * 112 + col] = acc_c[mt][nt][r];
                }
            }
        }
    }
    __syncthreads();

    int b_loc = tid >> 2;
    int quar  = tid & 3;
    float4 cr[28];
#pragma unroll
    for (int i = 0; i < 28; ++i) cr[i] = *(const float4*)(mvc + b_loc * 112 + i * 4);

    float part = 0.f;
    for (int pp = 0; pp < 28; ++pp) {
        int p = quar * 28 + pp;
        const float4* Grow = (const float4*)(G + p * NP);
        float wq = 0.f;
#pragma unroll 7
        for (int qq = 0; qq < 28; ++qq) {
            float4 g = Grow[qq];
            float4 m = cr[qq];
            wq += g.x * m.x + g.y * m.y + g.z * m.z + g.w * m.w;
        }
        float mtv = mvt[b_loc * 112 + p];
        float mcv = mvc[b_loc * 112 + p];
        part += mtv * wq + vvec[p] * (mtv + mcv);
    }
    part += __shfl_xor(part, 1);
    part += __shfl_xor(part, 2);

    float lossv = 0.f;
    if (quar == 0) {
        float logit = part + *c0p;
        float lab = labels[m0 + b_loc];
        lossv = fmaxf(logit, 0.f) - logit * lab + log1pf(expf(-fabsf(logit)));
    }
#pragma unroll
    for (int off = 4; off < 64; off <<= 1) lossv += __shfl_xor(lossv, off);
    if (lane == 0) bsum[w] = lossv;
    __syncthreads();
    if (tid == 0) {
        atomicAdd(out, (bsum[0] + bsum[1] + bsum[2] + bsum[3]) * (1.0f / 16384.0f));
    }
}

// ---------------------------------------------------------------------------
extern "C" void kernel_launch(void* const* d_in, const int* in_sizes, int n_in,
                              void* d_out, int out_size, void* d_ws, size_t ws_size,
                              hipStream_t stream) {
    const int*   targets    = (const int*)d_in[0];
    const int*   contexts   = (const int*)d_in[1];
    const float* times      = (const float*)d_in[2];
    const float* labels     = (const float*)d_in[3];
    const float* targetemb  = (const float*)d_in[4];
    const float* contextemb = (const float*)d_in[5];
    const float* h1_k       = (const float*)d_in[6];
    const float* h1_b       = (const float*)d_in[7];
    const float* h2_k       = (const float*)d_in[8];
    const float* h2_b       = (const float*)d_in[9];
    const float* evoke_k    = (const float*)d_in[10];
    const float* evoke_b    = (const float*)d_in[11];
    const float* last_k     = (const float*)d_in[12];
    const float* last_b     = (const float*)d_in[13];
    float* out = (float*)d_out;

    char* ws = (char*)d_ws;
    unsigned short* ekp = (unsigned short*)ws;                 // 301*28672 = 8,630,272
    unsigned short* tvp = (unsigned short*)(ws + 8630272);     // 16384*128*2 = 4,194,304
    float* G   = (float*)(ws + 8630272 + 4194304);             // 128*128*4   = 65,536
    float* vv  = (float*)(ws + 8630272 + 4194304 + 65536);     // 128*4
    float* c0  = (float*)(ws + 8630272 + 4194304 + 65536 + 512);

    k_ekprep<<<dim3(NE), dim3(256), 0, stream>>>(evoke_k, evoke_b, ekp);
    k_tv<<<dim3(BTOT / 16), dim3(256), 0, stream>>>(times, h1_k, h1_b, h2_k, h2_b, tvp);
    k_gprep<<<dim3(NP), dim3(128), 0, stream>>>(last_k, last_b, G, vv, c0, out);
    k_main<<<dim3(BTOT / BM), dim3(256), LDS_TOTAL, stream>>>(
        targets, contexts, labels, targetemb, contextemb, ekp, tvp, G, vv, c0, out);
}